// Round 2
// baseline (403.413 us; speedup 1.0000x reference)
//
#include <hip/hip_runtime.h>
#include <math.h>

// Problem constants (B,C,H,W) = (16,192,96,96), FILTERS = (1,3,3,3,3,1)
#define CC 192
#define BB 16
#define HWp 9216                       // 96*96
#define NPLANES (BB * CC)              // 3072
#define NELEM (BB * CC * HWp)          // 28311552

// LUT: v from VMIN, step dx = 1/17 EXACTLY, 1024 points.
// dx = 0.05882 vs previous 60/1023 = 0.05865 -> identical interp error (~1e-6).
// The exact-1/17 step makes v_i + 0.5 == v_{i+17} - 0.5, so the upper-chain
// of entry i IS the lower-chain of entry i+17: one shared array of
// NG = KLUT+17 sigmoid(chain(.)) values replaces 2*KLUT chain evals.
#define KLUT 1024
#define NG (KLUT + 17)                 // 1041
#define VMIN (-30.0f)
#define DXLUT (1.0f / 17.0f)
#define INV_DX 17.0f
#define OFFLUT 510.0f                  // -VMIN * 17

typedef float fvec4 __attribute__((ext_vector_type(4)));

__device__ __forceinline__ float fast_tanh(float x) {
    float e = __builtin_amdgcn_exp2f(x * 2.8853900817779268f);
    return 1.0f - 2.0f * __builtin_amdgcn_rcpf(e + 1.0f);
}

__device__ __forceinline__ float fast_sigmoid(float z) {
    float e = __builtin_amdgcn_exp2f(z * -1.4426950408889634f);
    return __builtin_amdgcn_rcpf(1.0f + e);
}

__device__ __forceinline__ float softplus_f(float x) {
    return (x > 20.0f) ? x : log1pf(expf(x));
}

struct Params {
    float W0[3], B0[3], T0[3];
    float W1[9], B1[3], T1[3];
    float W2[9], B2[3], T2[3];
    float W3[9], B3[3], T3[3];
    float W4[3], B4, T4;
};

#define EB_LAYER(OUT, IN, W, Bv, Tv)                                          \
    _Pragma("unroll")                                                         \
    for (int j = 0; j < 3; ++j) {                                             \
        float acc = fmaf((W)[j * 3 + 2], (IN)[2],                             \
                    fmaf((W)[j * 3 + 1], (IN)[1],                             \
                    fmaf((W)[j * 3 + 0], (IN)[0], (Bv)[j])));                 \
        (OUT)[j] = acc + (Tv)[j] * fast_tanh(acc);                            \
    }

__device__ __forceinline__ float chain(float u, const Params& P) {
    float h0[3], h1[3], h2[3], h3[3];
#pragma unroll
    for (int j = 0; j < 3; ++j) {
        float a = fmaf(P.W0[j], u, P.B0[j]);
        h0[j] = a + P.T0[j] * fast_tanh(a);
    }
    EB_LAYER(h1, h0, P.W1, P.B1, P.T1);
    EB_LAYER(h2, h1, P.W2, P.B2, P.T2);
    EB_LAYER(h3, h2, P.W3, P.B3, P.T3);
    float y = fmaf(P.W4[2], h3[2], fmaf(P.W4[1], h3[1], fmaf(P.W4[0], h3[0], P.B4)));
    y += P.T4 * fast_tanh(y);
    return y;
}

__device__ __forceinline__ void stage_params(
    int c, int t, float* sP,
    const float* m0, const float* b0, const float* f0,
    const float* m1, const float* b1, const float* f1,
    const float* m2, const float* b2, const float* f2,
    const float* m3, const float* b3, const float* f3,
    const float* m4, const float* b4, const float* f4)
{
    if (t < 59) {
        float val;
        if (t < 9) {
            int j = t % 3, w = t / 3;
            val = (w == 0) ? softplus_f(m0[c * 3 + j])
                : (w == 1) ? b0[c * 3 + j]
                           : tanhf(f0[c * 3 + j]);
        } else if (t < 54) {
            int u = t - 9;
            int l = u / 15, r = u % 15;
            const float* mm = (l == 0) ? m1 : (l == 1) ? m2 : m3;
            const float* bb = (l == 0) ? b1 : (l == 1) ? b2 : b3;
            const float* ff = (l == 0) ? f1 : (l == 1) ? f2 : f3;
            val = (r < 9)  ? softplus_f(mm[c * 9 + r])
                : (r < 12) ? bb[c * 3 + (r - 9)]
                           : tanhf(ff[c * 3 + (r - 12)]);
        } else {
            int r = t - 54;
            val = (r < 3)  ? softplus_f(m4[c * 3 + r])
                : (r == 3) ? b4[c]
                           : tanhf(f4[c]);
        }
        sP[t] = val;
    }
}

__device__ __forceinline__ void load_params(const float* sP, Params& P) {
#pragma unroll
    for (int j = 0; j < 3; ++j) { P.W0[j] = sP[j]; P.B0[j] = sP[3 + j]; P.T0[j] = sP[6 + j]; }
#pragma unroll
    for (int j = 0; j < 9; ++j) { P.W1[j] = sP[9 + j]; P.W2[j] = sP[24 + j]; P.W3[j] = sP[39 + j]; }
#pragma unroll
    for (int j = 0; j < 3; ++j) {
        P.B1[j] = sP[18 + j]; P.T1[j] = sP[21 + j];
        P.B2[j] = sP[33 + j]; P.T2[j] = sP[36 + j];
        P.B3[j] = sP[48 + j]; P.T3[j] = sP[51 + j];
        P.W4[j] = sP[54 + j];
    }
    P.B4 = sP[57];
    P.T4 = sP[58];
}

// pair-table lookup: one ds_read_b64 + interp. u >= 0 after clamp, so
// trunc == floor.
__device__ __forceinline__ float lut_lookup(const float2* sT, float v) {
    float u = fmaf(v, INV_DX, OFFLUT);
    u = fminf(fmaxf(u, 0.0f), (float)(KLUT - 1));   // v_med3_f32
    int idx = (int)u;
    float fr = u - (float)idx;
    float2 y = sT[idx];
    return fmaf(fr, y.y - y.x, y.x);
}

#define PROCESS_PAIR(a0, n0, a1, n1, i)                                       \
    do {                                                                      \
        fvec4 v0 = (a0) + (n0);                                               \
        fvec4 v1 = (a1) + (n1);                                               \
        fvec4 l0, l1;                                                         \
        l0.x = lut_lookup(sT, v0.x);  l0.y = lut_lookup(sT, v0.y);            \
        l0.z = lut_lookup(sT, v0.z);  l0.w = lut_lookup(sT, v0.w);            \
        l1.x = lut_lookup(sT, v1.x);  l1.y = lut_lookup(sT, v1.y);            \
        l1.z = lut_lookup(sT, v1.z);  l1.w = lut_lookup(sT, v1.w);            \
        __builtin_nontemporal_store(v0, ov0 + (i));                           \
        __builtin_nontemporal_store(l0, lv0 + (i));                           \
        __builtin_nontemporal_store(v1, ov1 + (i));                           \
        __builtin_nontemporal_store(l1, lv1 + (i));                           \
    } while (0)

// ---------------- single fused kernel ----------------
// grid (CC, BB/2): each block builds its channel's pair table in LDS via the
// shared-grid trick (1041 chain evals, ~half of before), with the first TWO
// stream iterations' global loads issued before the build so HBM stays busy
// under the table-build VALU work.
__global__ __launch_bounds__(256) void eb_all(
    const float* __restrict__ x, const float* __restrict__ nz,
    const float* __restrict__ m0, const float* __restrict__ b0, const float* __restrict__ f0,
    const float* __restrict__ m1, const float* __restrict__ b1, const float* __restrict__ f1,
    const float* __restrict__ m2, const float* __restrict__ b2, const float* __restrict__ f2,
    const float* __restrict__ m3, const float* __restrict__ b3, const float* __restrict__ f3,
    const float* __restrict__ m4, const float* __restrict__ b4, const float* __restrict__ f4,
    float* __restrict__ out)
{
    const int c = blockIdx.x;          // channel
    const int q = blockIdx.y;          // batch-pair index: planes 2q, 2q+1
    const int t = threadIdx.x;

    __shared__ float sP[59];
    __shared__ float sG[NG];           // sigmoid(chain(lower_i)), 4.1 KB
    __shared__ float2 sT[KLUT];        // 8 KB pair table

    const size_t base0 = ((size_t)(2 * q) * CC + c) * HWp;
    const size_t base1 = base0 + (size_t)CC * HWp;
    const fvec4* xv0 = (const fvec4*)(x + base0);
    const fvec4* nv0 = (const fvec4*)(nz + base0);
    fvec4* ov0 = (fvec4*)(out + base0);
    fvec4* lv0 = (fvec4*)(out + (size_t)NELEM + base0);
    const fvec4* xv1 = (const fvec4*)(x + base1);
    const fvec4* nv1 = (const fvec4*)(nz + base1);
    fvec4* ov1 = (fvec4*)(out + base1);
    fvec4* lv1 = (fvec4*)(out + (size_t)NELEM + base1);

    stage_params(c, t, sP, m0, b0, f0, m1, b1, f1, m2, b2, f2, m3, b3, f3, m4, b4, f4);
    __syncthreads();

    // Prefetch stream iterations k=0,1 AFTER the barrier (the compiler drains
    // vmcnt(0) at barriers; issuing here keeps the loads in flight across the
    // entire build phase, drained only at the post-build barrier).
    fvec4 pa0 = __builtin_nontemporal_load(xv0 + t);
    fvec4 pn0 = __builtin_nontemporal_load(nv0 + t);
    fvec4 pa1 = __builtin_nontemporal_load(xv1 + t);
    fvec4 pn1 = __builtin_nontemporal_load(nv1 + t);
    fvec4 qa0 = __builtin_nontemporal_load(xv0 + t + 256);
    fvec4 qn0 = __builtin_nontemporal_load(nv0 + t + 256);
    fvec4 qa1 = __builtin_nontemporal_load(xv1 + t + 256);
    fvec4 qn1 = __builtin_nontemporal_load(nv1 + t + 256);

    {
        Params P;
        load_params(sP, P);
#pragma unroll
        for (int k = 0; k < 4; ++k) {
            int i = t + k * 256;
            sG[i] = fast_sigmoid(chain(VMIN - 0.5f + (float)i * DXLUT, P));
        }
        if (t < NG - 4 * 256) {        // 17 tail entries
            int i = t + 1024;
            sG[i] = fast_sigmoid(chain(VMIN - 0.5f + (float)i * DXLUT, P));
        }
    }
    __syncthreads();
#pragma unroll
    for (int k = 0; k < 4; ++k) {
        int i = t + k * 256;
        float y0 = fmaxf(fabsf(sG[i + 17] - sG[i]), 1e-9f);
        float y1 = (i < KLUT - 1)
                 ? fmaxf(fabsf(sG[i + 18] - sG[i + 1]), 1e-9f)
                 : y0;
        sT[i] = make_float2(y0, y1);
    }
    __syncthreads();

    // consume the prefetched iterations first
    PROCESS_PAIR(pa0, pn0, pa1, pn1, t);
    PROCESS_PAIR(qa0, qn0, qa1, qn1, t + 256);

#pragma unroll 3
    for (int k = 2; k < (HWp / 4) / 256; ++k) {          // k = 2..8
        int i = t + k * 256;
        fvec4 a0 = __builtin_nontemporal_load(xv0 + i);
        fvec4 n0 = __builtin_nontemporal_load(nv0 + i);
        fvec4 a1 = __builtin_nontemporal_load(xv1 + i);
        fvec4 n1 = __builtin_nontemporal_load(nv1 + i);
        PROCESS_PAIR(a0, n0, a1, n1, i);
    }
}

extern "C" void kernel_launch(void* const* d_in, const int* in_sizes, int n_in,
                              void* d_out, int out_size, void* d_ws, size_t ws_size,
                              hipStream_t stream) {
    const float* x  = (const float*)d_in[0];
    const float* nz = (const float*)d_in[1];
    const float* m0 = (const float*)d_in[2];
    const float* b0 = (const float*)d_in[3];
    const float* f0 = (const float*)d_in[4];
    const float* m1 = (const float*)d_in[5];
    const float* b1 = (const float*)d_in[6];
    const float* f1 = (const float*)d_in[7];
    const float* m2 = (const float*)d_in[8];
    const float* b2 = (const float*)d_in[9];
    const float* f2 = (const float*)d_in[10];
    const float* m3 = (const float*)d_in[11];
    const float* b3 = (const float*)d_in[12];
    const float* f3 = (const float*)d_in[13];
    const float* m4 = (const float*)d_in[14];
    const float* b4 = (const float*)d_in[15];
    const float* f4 = (const float*)d_in[16];
    float* out = (float*)d_out;

    eb_all<<<dim3(CC, BB / 2), 256, 0, stream>>>(x, nz,
        m0, b0, f0, m1, b1, f1, m2, b2, f2, m3, b3, f3, m4, b4, f4, out);
}

// Round 3
// 398.536 us; speedup vs baseline: 1.0122x; 1.0122x over previous
//
#include <hip/hip_runtime.h>
#include <math.h>

// Problem constants (B,C,H,W) = (16,192,96,96), FILTERS = (1,3,3,3,3,1)
#define CC 192
#define BB 16
#define HWp 9216                       // 96*96
#define NPLANES (BB * CC)              // 3072
#define NELEM (BB * CC * HWp)          // 28311552

// LUT: v from VMIN, step dx = 1/17 EXACTLY, 1024 points.
// dx = 0.05882 vs 60/1023 = 0.05865 -> identical interp error (~1e-6).
// Exact-1/17 step makes v_i + 0.5 == v_{i+17} - 0.5, so the upper-chain of
// entry i IS the lower-chain of entry i+17: one shared array of
// NG = KLUT+17 sigmoid(chain(.)) values replaces 2*KLUT chain evals.
#define KLUT 1024
#define NG (KLUT + 17)                 // 1041
#define VMIN (-30.0f)
#define DXLUT (1.0f / 17.0f)
#define INV_DX 17.0f
#define OFFLUT 510.0f                  // -VMIN * 17

typedef float fvec4 __attribute__((ext_vector_type(4)));

__device__ __forceinline__ float fast_tanh(float x) {
    float e = __builtin_amdgcn_exp2f(x * 2.8853900817779268f);
    return 1.0f - 2.0f * __builtin_amdgcn_rcpf(e + 1.0f);
}

__device__ __forceinline__ float fast_sigmoid(float z) {
    float e = __builtin_amdgcn_exp2f(z * -1.4426950408889634f);
    return __builtin_amdgcn_rcpf(1.0f + e);
}

__device__ __forceinline__ float softplus_f(float x) {
    return (x > 20.0f) ? x : log1pf(expf(x));
}

struct Params {
    float W0[3], B0[3], T0[3];
    float W1[9], B1[3], T1[3];
    float W2[9], B2[3], T2[3];
    float W3[9], B3[3], T3[3];
    float W4[3], B4, T4;
};

#define EB_LAYER(OUT, IN, W, Bv, Tv)                                          \
    _Pragma("unroll")                                                         \
    for (int j = 0; j < 3; ++j) {                                             \
        float acc = fmaf((W)[j * 3 + 2], (IN)[2],                             \
                    fmaf((W)[j * 3 + 1], (IN)[1],                             \
                    fmaf((W)[j * 3 + 0], (IN)[0], (Bv)[j])));                 \
        (OUT)[j] = acc + (Tv)[j] * fast_tanh(acc);                            \
    }

__device__ __forceinline__ float chain(float u, const Params& P) {
    float h0[3], h1[3], h2[3], h3[3];
#pragma unroll
    for (int j = 0; j < 3; ++j) {
        float a = fmaf(P.W0[j], u, P.B0[j]);
        h0[j] = a + P.T0[j] * fast_tanh(a);
    }
    EB_LAYER(h1, h0, P.W1, P.B1, P.T1);
    EB_LAYER(h2, h1, P.W2, P.B2, P.T2);
    EB_LAYER(h3, h2, P.W3, P.B3, P.T3);
    float y = fmaf(P.W4[2], h3[2], fmaf(P.W4[1], h3[1], fmaf(P.W4[0], h3[0], P.B4)));
    y += P.T4 * fast_tanh(y);
    return y;
}

__device__ __forceinline__ void stage_params(
    int c, int t, float* sP,
    const float* m0, const float* b0, const float* f0,
    const float* m1, const float* b1, const float* f1,
    const float* m2, const float* b2, const float* f2,
    const float* m3, const float* b3, const float* f3,
    const float* m4, const float* b4, const float* f4)
{
    if (t < 59) {
        float val;
        if (t < 9) {
            int j = t % 3, w = t / 3;
            val = (w == 0) ? softplus_f(m0[c * 3 + j])
                : (w == 1) ? b0[c * 3 + j]
                           : tanhf(f0[c * 3 + j]);
        } else if (t < 54) {
            int u = t - 9;
            int l = u / 15, r = u % 15;
            const float* mm = (l == 0) ? m1 : (l == 1) ? m2 : m3;
            const float* bb = (l == 0) ? b1 : (l == 1) ? b2 : b3;
            const float* ff = (l == 0) ? f1 : (l == 1) ? f2 : f3;
            val = (r < 9)  ? softplus_f(mm[c * 9 + r])
                : (r < 12) ? bb[c * 3 + (r - 9)]
                           : tanhf(ff[c * 3 + (r - 12)]);
        } else {
            int r = t - 54;
            val = (r < 3)  ? softplus_f(m4[c * 3 + r])
                : (r == 3) ? b4[c]
                           : tanhf(f4[c]);
        }
        sP[t] = val;
    }
}

__device__ __forceinline__ void load_params(const float* sP, Params& P) {
#pragma unroll
    for (int j = 0; j < 3; ++j) { P.W0[j] = sP[j]; P.B0[j] = sP[3 + j]; P.T0[j] = sP[6 + j]; }
#pragma unroll
    for (int j = 0; j < 9; ++j) { P.W1[j] = sP[9 + j]; P.W2[j] = sP[24 + j]; P.W3[j] = sP[39 + j]; }
#pragma unroll
    for (int j = 0; j < 3; ++j) {
        P.B1[j] = sP[18 + j]; P.T1[j] = sP[21 + j];
        P.B2[j] = sP[33 + j]; P.T2[j] = sP[36 + j];
        P.B3[j] = sP[48 + j]; P.T3[j] = sP[51 + j];
        P.W4[j] = sP[54 + j];
    }
    P.B4 = sP[57];
    P.T4 = sP[58];
}

// pair-table lookup: one ds_read_b64 + interp. u >= 0 after clamp, so
// trunc == floor.
__device__ __forceinline__ float lut_lookup(const float2* sT, float v) {
    float u = fmaf(v, INV_DX, OFFLUT);
    u = fminf(fmaxf(u, 0.0f), (float)(KLUT - 1));   // v_med3_f32
    int idx = (int)u;
    float fr = u - (float)idx;
    float2 y = sT[idx];
    return fmaf(fr, y.y - y.x, y.x);
}

// ---------------- single fused kernel ----------------
// grid (CC, BB/2): each block builds its channel's pair table in LDS via the
// shared-grid trick (1041 chain evals), then streams 2 planes. This is the
// round-1 stream structure (best measured) with the half-build retained and
// the register prefetch removed (bundled-change post-mortem: prefetch was
// the regression suspect; half-build is strictly less work).
__global__ __launch_bounds__(256) void eb_all(
    const float* __restrict__ x, const float* __restrict__ nz,
    const float* __restrict__ m0, const float* __restrict__ b0, const float* __restrict__ f0,
    const float* __restrict__ m1, const float* __restrict__ b1, const float* __restrict__ f1,
    const float* __restrict__ m2, const float* __restrict__ b2, const float* __restrict__ f2,
    const float* __restrict__ m3, const float* __restrict__ b3, const float* __restrict__ f3,
    const float* __restrict__ m4, const float* __restrict__ b4, const float* __restrict__ f4,
    float* __restrict__ out)
{
    const int c = blockIdx.x;          // channel
    const int q = blockIdx.y;          // batch-pair index: planes 2q, 2q+1
    const int t = threadIdx.x;

    __shared__ float sP[59];
    __shared__ float sG[NG];           // sigmoid(chain(lower_i)), 4.1 KB
    __shared__ float2 sT[KLUT];        // 8 KB pair table

    stage_params(c, t, sP, m0, b0, f0, m1, b1, f1, m2, b2, f2, m3, b3, f3, m4, b4, f4);
    __syncthreads();
    {
        Params P;
        load_params(sP, P);
#pragma unroll
        for (int k = 0; k < 4; ++k) {
            int i = t + k * 256;
            sG[i] = fast_sigmoid(chain(VMIN - 0.5f + (float)i * DXLUT, P));
        }
        if (t < NG - 4 * 256) {        // 17 tail entries
            int i = t + 1024;
            sG[i] = fast_sigmoid(chain(VMIN - 0.5f + (float)i * DXLUT, P));
        }
    }
    __syncthreads();
#pragma unroll
    for (int k = 0; k < 4; ++k) {
        int i = t + k * 256;
        float y0 = fmaxf(fabsf(sG[i + 17] - sG[i]), 1e-9f);
        float y1 = (i < KLUT - 1)
                 ? fmaxf(fabsf(sG[i + 18] - sG[i + 1]), 1e-9f)
                 : y0;
        sT[i] = make_float2(y0, y1);
    }
    __syncthreads();

    const size_t base0 = ((size_t)(2 * q) * CC + c) * HWp;
    const size_t base1 = base0 + (size_t)CC * HWp;

    const fvec4* xv0 = (const fvec4*)(x + base0);
    const fvec4* nv0 = (const fvec4*)(nz + base0);
    fvec4* ov0 = (fvec4*)(out + base0);
    fvec4* lv0 = (fvec4*)(out + (size_t)NELEM + base0);
    const fvec4* xv1 = (const fvec4*)(x + base1);
    const fvec4* nv1 = (const fvec4*)(nz + base1);
    fvec4* ov1 = (fvec4*)(out + base1);
    fvec4* lv1 = (fvec4*)(out + (size_t)NELEM + base1);

#pragma unroll 3
    for (int k = 0; k < (HWp / 4) / 256; ++k) {          // 9 iters, 2 planes each
        int i = t + k * 256;
        fvec4 a0 = __builtin_nontemporal_load(xv0 + i);
        fvec4 n0 = __builtin_nontemporal_load(nv0 + i);
        fvec4 a1 = __builtin_nontemporal_load(xv1 + i);
        fvec4 n1 = __builtin_nontemporal_load(nv1 + i);
        fvec4 v0 = a0 + n0;
        fvec4 v1 = a1 + n1;
        fvec4 l0, l1;
        l0.x = lut_lookup(sT, v0.x);  l0.y = lut_lookup(sT, v0.y);
        l0.z = lut_lookup(sT, v0.z);  l0.w = lut_lookup(sT, v0.w);
        l1.x = lut_lookup(sT, v1.x);  l1.y = lut_lookup(sT, v1.y);
        l1.z = lut_lookup(sT, v1.z);  l1.w = lut_lookup(sT, v1.w);
        __builtin_nontemporal_store(v0, ov0 + i);
        __builtin_nontemporal_store(l0, lv0 + i);
        __builtin_nontemporal_store(v1, ov1 + i);
        __builtin_nontemporal_store(l1, lv1 + i);
    }
}

extern "C" void kernel_launch(void* const* d_in, const int* in_sizes, int n_in,
                              void* d_out, int out_size, void* d_ws, size_t ws_size,
                              hipStream_t stream) {
    const float* x  = (const float*)d_in[0];
    const float* nz = (const float*)d_in[1];
    const float* m0 = (const float*)d_in[2];
    const float* b0 = (const float*)d_in[3];
    const float* f0 = (const float*)d_in[4];
    const float* m1 = (const float*)d_in[5];
    const float* b1 = (const float*)d_in[6];
    const float* f1 = (const float*)d_in[7];
    const float* m2 = (const float*)d_in[8];
    const float* b2 = (const float*)d_in[9];
    const float* f2 = (const float*)d_in[10];
    const float* m3 = (const float*)d_in[11];
    const float* b3 = (const float*)d_in[12];
    const float* f3 = (const float*)d_in[13];
    const float* m4 = (const float*)d_in[14];
    const float* b4 = (const float*)d_in[15];
    const float* f4 = (const float*)d_in[16];
    float* out = (float*)d_out;

    eb_all<<<dim3(CC, BB / 2), 256, 0, stream>>>(x, nz,
        m0, b0, f0, m1, b1, f1, m2, b2, f2, m3, b3, f3, m4, b4, f4, out);
}